// Round 6
// baseline (397.162 us; speedup 1.0000x reference)
//
#include <hip/hip_runtime.h>

#define HBV_B    1024
#define HBV_NZ   1e-5f
#define LDSTR    64            // floats per step slot (one per lane)
#define BUFSZ    (15 * LDSTR)  // one 15-step chunk buffer

// ---------------------------------------------------------------------------
// 3-stage pipeline over 2 waves (one block = 128 threads on one CU):
//   wave 1: snow recurrence (forcing-only) one chunk AHEAD -> rt, log2(PET)
//           via LDS; routing FIR + DPP mean + store one chunk BEHIND.
//   wave 0: the coupled SM/SLZ/SUZ core. Its SM self-loop is the structural
//           critical path. R5 measurement: v_log/v_exp dependent latency
//           ~55 cyc each (4 chained = ~220 of 322 cyc/step). This revision
//           replaces them with full-rate-VALU bit-hack log2/exp2:
//             fast_log2: exponent split at sqrt(0.5) + Cephes deg-6 mantissa
//                        poly (Estrin), depth ~9 deps ~36 cyc, err ~2e-5.
//             fast_exp2: rndne split + Cephes deg-5 poly + integer exponent
//                        add, depth ~7 deps ~28 cyc, err ~1e-7 rel.
//           Chain: ~250 cyc -> ~165 cyc.
// Phase p: wave0 soil chunk p-1; wave1 snow chunk p + route chunk p-2.
// rt/lp/q double-buffered by chunk parity; 135 barriers.
// ---------------------------------------------------------------------------

struct F3 { float x, y, z; };   // 12B forcing record (P, T, PET)

// x += lane-rotated x within the 16-lane DPP row (row_ror:N = 0x120+N).
#define DPP_ADD_ROR(x, ctrl) do {                                              \
    int _r = __builtin_amdgcn_update_dpp(0, __float_as_int(x),                 \
                                         (ctrl), 0xF, 0xF, true);              \
    (x) += __int_as_float(_r);                                                 \
} while (0)

// ---- full-rate VALU log2: valid for normal x > 0 --------------------------
__device__ __forceinline__ float fast_log2(float x) {
    int   i  = __float_as_int(x);
    int   a  = i - 0x3f3504f3;            // split at sqrt(0.5)
    int   eb = a & (int)0xff800000;       // e << 23 (sign-safe via arith &)
    float m  = __int_as_float(i - eb);    // m in [sqrt(.5), sqrt(2))
    float ef = (float)(eb >> 23);         // arithmetic shift
    float t  = m - 1.0f;                  // t in [-0.2929, 0.4142]
    float t2 = t * t;
    // ln(1+t) = t - t^2/2 + t^3 * P(t); Cephes logf P truncated to deg-6
    float A  = __builtin_fmaf(-2.4999993993e-1f, t, 3.3333331174e-1f);
    float B  = __builtin_fmaf(-1.6668057665e-1f, t, 2.0000714765e-1f);
    float C  = __builtin_fmaf(-1.2420140846e-1f, t, 1.4249322787e-1f);
    float t4 = t2 * t2;
    float D  = __builtin_fmaf(B, t2, A);
    float E  = __builtin_fmaf(1.1676998740e-1f, t2, C);
    float P  = __builtin_fmaf(E, t4, D);
    float t3 = t * t2;
    float ln = __builtin_fmaf(t3, P, __builtin_fmaf(-0.5f, t2, t));
    return __builtin_fmaf(1.4426950408889634f, ln, ef);
}

// ---- full-rate VALU exp2: valid for x in [-125, 3] ------------------------
__device__ __forceinline__ float fast_exp2(float x) {
    float n  = __builtin_rintf(x);        // v_rndne
    float f  = x - n;                     // f in [-0.5, 0.5]
    int   ni = (int)n;
    float f2 = f * f;
    // 2^f = 1 + f * P(f); Cephes exp2f deg-5 P
    float A  = __builtin_fmaf(2.402264791363012e-1f, f, 6.931472028550421e-1f);
    float B  = __builtin_fmaf(9.618437357674640e-3f, f, 5.550332471162809e-2f);
    float C  = __builtin_fmaf(1.535336188319500e-4f, f, 1.339887440266574e-3f);
    float D  = __builtin_fmaf(C, f2, B);
    float E  = __builtin_fmaf(D, f2, A);
    float r  = __builtin_fmaf(f, E, 1.0f);            // in [0.707, 1.415]
    return __int_as_float(__float_as_int(r) + (ni << 23));
}

// ---- stage B: soil step (critical wave). rt/lp pre-read from LDS. ---------
// lp = log2(PET) pre-clamped to >= -118 by wave1.
#define SOIL_STEP(s, rt_, lp_, qdst) do {                                      \
    float rt   = (rt_);                                                        \
    float lp   = (lp_);                                                        \
    /* off-chain helpers */                                                    \
    float cpet = lp + nBEloglpfc;                                              \
    float CSLZ = parC * SLZ;                                                   \
    float c1   = __builtin_fmaf(-CSLZ, invFC, 1.0f);                           \
    float SMrt = SM + rt;                                                      \
    /* ---- cross-step critical chain ---- */                                  \
    float lSM = fast_log2(SM);                                                 \
    float esw = __builtin_fmaf(parBETA, lSM, nBlogFC);                         \
    esw = fminf(fmaxf(esw, -120.0f), 0.0f);                                    \
    float sw  = fast_exp2(esw);                                                \
    float SM1 = __builtin_fmaf(-rt, sw, SMrt);                                 \
    float SM2 = fminf(SM1, parFC);                                             \
    float SM3 = __builtin_fmaf(SM2, c1, CSLZ);                                 \
    float lS3 = fast_log2(SM3);                                                \
    float eef = __builtin_fmaf(parBETAET, lS3, cpet);                          \
    eef = fminf(fmaxf(eef, -120.0f), lp);      /* lp >= -118 */                \
    float PETef = fast_exp2(eef);                                              \
    SM = fmaxf(SM3 - PETef, HBV_NZ);                                           \
    /* ---- off-chain: SUZ/SLZ and Qsim export ---- */                         \
    float recharge  = rt * sw;                                                 \
    float excess    = SM1 - SM2;                                               \
    float capillary = SM3 - SM2;                                               \
    SUZ = SUZ + recharge + excess;                                             \
    float PERCa = fminf(SUZ, parPERC);                                         \
    float A_ = SUZ - PERCa;                                                    \
    float B_ = fminf(A_, __builtin_fmaf(K0c, A_, K0UZL)); /* post-Q0 */        \
    SUZ = K1c * B_;                            /* post-Q1 */                   \
    float SLZnew = SLZ - capillary + PERCa;                                    \
    SLZ = K2c * SLZnew;                                                        \
    /* Qsim = Q0+Q1+Q2 = (A_ - SUZ_next) + K2*SLZnew */                        \
    (qdst)[(s) * LDSTR] = __builtin_fmaf(parK2, SLZnew, A_ - SUZ);             \
} while (0)

#define SOIL_CHUNK(nsteps, rts, lps, qds) do {                                 \
    float rr[15], lpv[15];                                                     \
    _Pragma("unroll")                                                          \
    for (int k_ = 0; k_ < (nsteps); ++k_) {                                    \
        rr[k_]  = (rts)[k_ * LDSTR];                                           \
        lpv[k_] = (lps)[k_ * LDSTR];                                           \
    }                                                                          \
    _Pragma("unroll")                                                          \
    for (int s_ = 0; s_ < (nsteps); ++s_)                                      \
        SOIL_STEP(s_, rr[s_], lpv[s_], qds);                                   \
} while (0)

// ---- stage A: snow step (forcing-only) -> rt, clamped log2(PET) to LDS ----
#define SNOW_STEP(s, Pm, Tc, PETm, rts, lps) do {                              \
    float rain = ((Tc) >= parTT) ? (Pm) : 0.0f;                                \
    float snow = (Pm) - rain;                                                  \
    SNOW += snow;                                                              \
    float melt = fminf(fmaxf(__builtin_fmaf(parCFMAX, (Tc), negCT), 0.0f),     \
                       SNOW);                                                  \
    MELT += melt; SNOW -= melt;                                                \
    float refreeze = fminf(fmaxf(__builtin_fmaf(-CFRC, (Tc), CFRCTT), 0.0f),   \
                           MELT);                                              \
    SNOW += refreeze; MELT -= refreeze;                                        \
    float tosoil = fmaxf(__builtin_fmaf(-parCWH, SNOW, MELT), 0.0f);           \
    MELT -= tosoil;                                                            \
    (rts)[(s) * LDSTR] = rain + tosoil;                                        \
    (lps)[(s) * LDSTR] = fmaxf(__builtin_amdgcn_logf(PETm), -118.0f);          \
} while (0)

#define SNOW_CHUNK(nsteps, Pf, Tf, Ef, rts, lps) do {                          \
    _Pragma("unroll")                                                          \
    for (int s_ = 0; s_ < (nsteps); ++s_)                                      \
        SNOW_STEP(s_, (Pf)[s_], (Tf)[s_], (Ef)[s_], rts, lps);                 \
} while (0)

#define LOAD_CHUNK(nsteps, Pf, Tf, Ef, tbase) do {                             \
    _Pragma("unroll")                                                          \
    for (int k_ = 0; k_ < (nsteps); ++k_) {                                    \
        F3 _f = xb3[(size_t)((tbase) + k_) * HBV_B];                           \
        (Pf)[k_] = _f.x; (Tf)[k_] = _f.y; (Ef)[k_] = _f.z;                     \
    }                                                                          \
} while (0)

// ---- stage C: routing. Chunk bases are multiples of 15 -> ring slot == s. -
#define ROUTE_STEP(s, tb) do {                                                 \
    q[(s)] = qq[(s)];                                                          \
    float qr = 0.0f;                                                           \
    _Pragma("unroll")                                                          \
    for (int k_ = 0; k_ < 15; ++k_)                                            \
        qr += w[k_] * q[((s) - k_ + 15) % 15];                                 \
    DPP_ADD_ROR(qr, 0x128);                                                    \
    DPP_ADD_ROR(qr, 0x124);                                                    \
    DPP_ADD_ROR(qr, 0x122);                                                    \
    DPP_ADD_ROR(qr, 0x121);                                                    \
    if (m == 0) out[(size_t)((tb) + (s)) * HBV_B + b] = qr;                    \
} while (0)

#define ROUTE_CHUNK(nsteps, qsrc, tb) do {                                     \
    float qq[15];                                                              \
    _Pragma("unroll")                                                          \
    for (int k_ = 0; k_ < (nsteps); ++k_) qq[k_] = (qsrc)[k_ * LDSTR];         \
    _Pragma("unroll")                                                          \
    for (int s_ = 0; s_ < (nsteps); ++s_) ROUTE_STEP(s_, tb);                  \
} while (0)

__global__ __launch_bounds__(128, 1)
void hbv_pipe3_kernel(const float* __restrict__ x_phy,   // (2000, 1024, 3)
                      const float* __restrict__ ps,      // (1024, 288)
                      float* __restrict__ out)           // (2000, 1024)
{
    const int lane = (int)threadIdx.x & 63;
    const int wave = (int)threadIdx.x >> 6;
    const int b = blockIdx.x * 4 + (lane >> 4);
    const int m = lane & 15;

    __shared__ float qbuf [2 * BUFSZ];   // Qsim chunks   (soil -> route)
    __shared__ float rtbuf[2 * BUFSZ];   // rain+tosoil   (snow -> soil)
    __shared__ float lpbuf[2 * BUFSZ];   // log2(PET)     (snow -> soil)

    const float* __restrict__ pb = ps + (size_t)b * 288;

    if (wave == 0) {
        // ---------------- stage B: soil (critical wave) --------------------
        const float parBETA   = 1.0f   + pb[ 0*16 + m] * 5.0f;
        const float parFC     = 50.0f  + pb[ 1*16 + m] * 950.0f;
        const float parK0     = 0.05f  + pb[ 2*16 + m] * 0.85f;
        const float parK1     = 0.01f  + pb[ 3*16 + m] * 0.49f;
        const float parK2     = 0.001f + pb[ 4*16 + m] * 0.199f;
        const float parLP     = 0.2f   + pb[ 5*16 + m] * 0.8f;
        const float parPERC   =          pb[ 6*16 + m] * 10.0f;
        const float parUZL    =          pb[ 7*16 + m] * 100.0f;
        const float parBETAET = 0.3f   + pb[12*16 + m] * 4.7f;
        const float parC      =          pb[13*16 + m];

        const float invFC   = 1.0f / parFC;
        const float K0c     = 1.0f - parK0;
        const float K0UZL   = parK0 * parUZL;
        const float K1c     = 1.0f - parK1;
        const float K2c     = 1.0f - parK2;
        const float nBlogFC    = -parBETA   * __builtin_amdgcn_logf(parFC);
        const float nBEloglpfc = -parBETAET * __builtin_amdgcn_logf(parLP * parFC);

        float SM = HBV_NZ, SUZ = HBV_NZ, SLZ = HBV_NZ;

        float* const qb0 = &qbuf [lane];
        float* const qb1 = &qbuf [BUFSZ + lane];
        const float* const rb0 = &rtbuf[lane];
        const float* const rb1 = &rtbuf[BUFSZ + lane];
        const float* const lb0 = &lpbuf[lane];
        const float* const lb1 = &lpbuf[BUFSZ + lane];

        __syncthreads();                                   // p=0 (snow c0)
#pragma unroll 1
        for (int jj = 0; jj < 66; ++jj) {                  // chunks 0..131
            SOIL_CHUNK(15, rb0, lb0, qb0); __syncthreads();
            SOIL_CHUNK(15, rb1, lb1, qb1); __syncthreads();
        }
        SOIL_CHUNK(15, rb0, lb0, qb0); __syncthreads();    // chunk 132
        SOIL_CHUNK( 5, rb1, lb1, qb1); __syncthreads();    // chunk 133 (tail)
        // 135 barriers total.
    } else {
        // ------------- stages A + C: snow (ahead) + routing (behind) -------
        const float parTT     = -2.5f  + pb[ 8*16 + m] * 5.0f;
        const float parCFMAX  = 0.5f   + pb[ 9*16 + m] * 9.5f;
        const float parCFR    =          pb[10*16 + m] * 0.1f;
        const float parCWH    =          pb[11*16 + m] * 0.2f;
        const float rout_a    =          pb[256 + m]      * 2.9f;
        const float rout_b    =          pb[256 + 16 + m] * 6.5f;

        const float CFRC   = parCFR * parCFMAX;
        const float negCT  = -parCFMAX * parTT;
        const float CFRCTT =  CFRC * parTT;

        // w[k] ∝ t_k^(a-1) exp(-t_k/theta); Gamma/theta^a cancels under the
        // normalization. Pre-scaled by 1/16 to fold in the mean over m.
        const float aa    = fmaxf(rout_a, 0.0f) + 0.1f;
        const float theta = fmaxf(rout_b, 0.0f) + 0.5f;
        const float am1   = aa - 1.0f;
        const float nit   = -1.4426950408889634f / theta;
        float w[15];
        float wsum = 0.0f;
#pragma unroll
        for (int k = 0; k < 15; ++k) {
            float tk = (float)k + 0.5f;
            float e  = am1 * __builtin_amdgcn_logf(tk) + nit * tk;
            w[k] = __builtin_amdgcn_exp2f(e);
            wsum += w[k];
        }
        const float wscale = 1.0f / (16.0f * wsum);
#pragma unroll
        for (int k = 0; k < 15; ++k) w[k] *= wscale;

        float q[15];
#pragma unroll
        for (int k = 0; k < 15; ++k) q[k] = 0.0f;

        float SNOW = HBV_NZ, MELT = HBV_NZ;

        float* const rb0 = &rtbuf[lane];
        float* const rb1 = &rtbuf[BUFSZ + lane];
        float* const lb0 = &lpbuf[lane];
        float* const lb1 = &lpbuf[BUFSZ + lane];
        const float* const qb0 = &qbuf[lane];
        const float* const qb1 = &qbuf[BUFSZ + lane];

        const F3* __restrict__ xb3 = (const F3*)x_phy + b;
        float PA[15], TA[15], EA[15], PB[15], TB[15], EB[15];

        LOAD_CHUNK(15, PA, TA, EA, 0);
        // p=0: snow c0 -> rt0; prefetch c1
        SNOW_CHUNK(15, PA, TA, EA, rb0, lb0);
        LOAD_CHUNK(15, PB, TB, EB, 15);
        __syncthreads();
        // p=1: snow c1 -> rt1; prefetch c2
        SNOW_CHUNK(15, PB, TB, EB, rb1, lb1);
        LOAD_CHUNK(15, PA, TA, EA, 30);
        __syncthreads();
        // p=2..131 (65 double-phases): snow c=p, prefetch c=p+1, route c=p-2
#pragma unroll 1
        for (int jj = 1; jj <= 65; ++jj) {
            SNOW_CHUNK(15, PA, TA, EA, rb0, lb0);          // chunk 2jj (even)
            LOAD_CHUNK(15, PB, TB, EB, 15 * (2 * jj + 1));
            ROUTE_CHUNK(15, qb0, 15 * (2 * jj - 2));       // chunk 2jj-2
            __syncthreads();
            SNOW_CHUNK(15, PB, TB, EB, rb1, lb1);          // chunk 2jj+1
            LOAD_CHUNK(15, PA, TA, EA, 15 * (2 * jj + 2));
            ROUTE_CHUNK(15, qb1, 15 * (2 * jj - 1));       // chunk 2jj-1
            __syncthreads();
        }
        // p=132: snow c132 -> rt0; prefetch tail (5); route c130
        SNOW_CHUNK(15, PA, TA, EA, rb0, lb0);
        LOAD_CHUNK(5, PB, TB, EB, 1995);
        ROUTE_CHUNK(15, qb0, 1950);
        __syncthreads();
        // p=133: snow tail c133 (5) -> rt1; route c131
        SNOW_CHUNK(5, PB, TB, EB, rb1, lb1);
        ROUTE_CHUNK(15, qb1, 1965);
        __syncthreads();
        // p=134: route c132
        ROUTE_CHUNK(15, qb0, 1980);
        __syncthreads();
        // p=135: route tail c133 (5)
        ROUTE_CHUNK(5, qb1, 1995);
        // 135 barriers total.
    }
}

extern "C" void kernel_launch(void* const* d_in, const int* in_sizes, int n_in,
                              void* d_out, int out_size, void* d_ws, size_t ws_size,
                              hipStream_t stream) {
    const float* x_phy = (const float*)d_in[0];   // (2000,1024,3) fp32
    const float* ps    = (const float*)d_in[1];   // (1024,288)    fp32
    float* out         = (float*)d_out;           // (2000,1024)   fp32

    // 256 blocks x 128 threads. Wall time = soil wave's SM-chain latency
    // x 2000 steps; chain now built from full-rate VALU ops only.
    hbv_pipe3_kernel<<<256, 128, 0, stream>>>(x_phy, ps, out);
}